// Round 1
// baseline (1592.281 us; speedup 1.0000x reference)
//
#include <hip/hip_runtime.h>

#define H 128

// ---------------------------------------------------------------------------
// GEMM: X0 = notes @ w  [n_nodes x 128] = [n_nodes x 128] @ [128 x 128]
// w staged in LDS (64KB). Each wave: 4 rows, each lane: cols (lane, lane+64).
// Also writes rows >= garment directly to the output tail (concat part 2).
// ---------------------------------------------------------------------------
__global__ __launch_bounds__(256) void gemm_kernel(
    const float* __restrict__ notes, const float* __restrict__ w,
    const int* __restrict__ g_ptr, float* __restrict__ x0,
    float* __restrict__ out, int n_nodes) {
  __shared__ float wlds[H * H];  // 64 KB
  {
    const float4* w4 = (const float4*)w;
    float4* wl4 = (float4*)wlds;
    for (int i = threadIdx.x; i < (H * H) / 4; i += blockDim.x) wl4[i] = w4[i];
  }
  __syncthreads();

  const int wave = threadIdx.x >> 6;
  const int lane = threadIdx.x & 63;
  const int g = *g_ptr;
  const int rowBase = (blockIdx.x * 4 + wave) * 4;
  if (rowBase >= n_nodes) return;

  // Clamp row indices for safe loads; stores are guarded.
  const int r0 = rowBase;
  const int r1 = min(rowBase + 1, n_nodes - 1);
  const int r2 = min(rowBase + 2, n_nodes - 1);
  const int r3 = min(rowBase + 3, n_nodes - 1);
  const float* nr0 = notes + (size_t)r0 * H;
  const float* nr1 = notes + (size_t)r1 * H;
  const float* nr2 = notes + (size_t)r2 * H;
  const float* nr3 = notes + (size_t)r3 * H;

  float a00 = 0.f, a01 = 0.f, a10 = 0.f, a11 = 0.f;
  float a20 = 0.f, a21 = 0.f, a30 = 0.f, a31 = 0.f;
#pragma unroll 4
  for (int k = 0; k < H; ++k) {
    const float w0 = wlds[k * H + lane];
    const float w1 = wlds[k * H + lane + 64];
    const float n0 = nr0[k];
    const float n1 = nr1[k];
    const float n2 = nr2[k];
    const float n3 = nr3[k];
    a00 += n0 * w0; a01 += n0 * w1;
    a10 += n1 * w0; a11 += n1 * w1;
    a20 += n2 * w0; a21 += n2 * w1;
    a30 += n3 * w0; a31 += n3 * w1;
  }

  float lo[4] = {a00, a10, a20, a30};
  float hi[4] = {a01, a11, a21, a31};
#pragma unroll
  for (int i = 0; i < 4; ++i) {
    const int r = rowBase + i;
    if (r < n_nodes) {
      x0[(size_t)r * H + lane] = lo[i];
      x0[(size_t)r * H + lane + 64] = hi[i];
      if (r >= g) {
        const size_t o = (size_t)(n_nodes + r - g) * H;
        out[o + lane] = lo[i];
        out[o + lane + 64] = hi[i];
      }
    }
  }
}

// ---------------------------------------------------------------------------
// Scatter: for each edge e: acc[src[e]][:] += ew[e] * X0[dst[e]][:]
// One wave per edge; lane handles elements (2*lane, 2*lane+1).
// ---------------------------------------------------------------------------
__global__ __launch_bounds__(256) void scatter_kernel(
    const int* __restrict__ esrc, const int* __restrict__ edst,
    const float* __restrict__ ew, const float* __restrict__ x0,
    float* __restrict__ acc, int n_edges) {
  const int lane = threadIdx.x & 63;
  const int wavesPerBlock = blockDim.x >> 6;
  const int waveId = blockIdx.x * wavesPerBlock + (threadIdx.x >> 6);
  const int nWaves = gridDim.x * wavesPerBlock;
  const float2* __restrict__ x0v = (const float2*)x0;

  for (int e = waveId; e < n_edges; e += nWaves) {
    const int s = esrc[e];
    const int d = edst[e];
    const float wt = ew[e];
    const float2 v = x0v[(size_t)d * 64 + lane];
    float* p = acc + (size_t)s * H + lane * 2;
    atomicAdd(p, v.x * wt);
    atomicAdd(p + 1, v.y * wt);
  }
}

// ---------------------------------------------------------------------------
// Epilogue: out[i] = relu(out[i] + b[col]) over the first n_nodes*H floats.
// ---------------------------------------------------------------------------
__global__ __launch_bounds__(256) void epilogue_kernel(
    float* __restrict__ out, const float* __restrict__ b, int n4) {
  const int i = blockIdx.x * blockDim.x + threadIdx.x;
  if (i >= n4) return;
  float4* o4 = (float4*)out;
  const float4* b4 = (const float4*)b;
  float4 v = o4[i];
  const float4 bb = b4[i & 31];  // (4*i) % 128 / 4
  v.x = fmaxf(v.x + bb.x, 0.f);
  v.y = fmaxf(v.y + bb.y, 0.f);
  v.z = fmaxf(v.z + bb.z, 0.f);
  v.w = fmaxf(v.w + bb.w, 0.f);
  o4[i] = v;
}

extern "C" void kernel_launch(void* const* d_in, const int* in_sizes, int n_in,
                              void* d_out, int out_size, void* d_ws, size_t ws_size,
                              hipStream_t stream) {
  const float* notes = (const float*)d_in[0];
  const float* w     = (const float*)d_in[1];
  const float* b     = (const float*)d_in[2];
  const int*   esrc  = (const int*)d_in[3];
  const int*   edst  = (const int*)d_in[4];
  const float* ew    = (const float*)d_in[5];
  const int*   gptr  = (const int*)d_in[6];

  const int n_nodes = in_sizes[0] / H;
  const int n_edges = in_sizes[3];

  float* x0  = (float*)d_ws;            // n_nodes*H floats = 51.2 MB
  float* out = (float*)d_out;

  // Zero the accumulator region (first n_nodes*H floats of out).
  hipMemsetAsync(d_out, 0, (size_t)n_nodes * H * sizeof(float), stream);

  // X0 = notes @ w; tail rows copied straight to out.
  gemm_kernel<<<(n_nodes + 15) / 16, 256, 0, stream>>>(notes, w, gptr, x0, out,
                                                       n_nodes);

  // Edge scatter with fp32 atomics into out[0 : n_nodes*H].
  scatter_kernel<<<2048, 256, 0, stream>>>(esrc, edst, ew, x0, out, n_edges);

  // out = relu(out + b) in place.
  const int n4 = n_nodes * H / 4;
  epilogue_kernel<<<(n4 + 255) / 256, 256, 0, stream>>>(out, b, n4);
}

// Round 2
// 529.681 us; speedup vs baseline: 3.0061x; 3.0061x over previous
//
#include <hip/hip_runtime.h>

#define H 128
#define SCAN_B 512

// ---------------------------------------------------------------------------
// GEMM: X0 = notes @ w. w (64KB) + 16 note-rows (8KB) staged in LDS.
// Each wave: 4 rows; each lane: cols (lane, lane+64).
// Rows >= garment_size also written straight to the output tail (concat pt 2).
// ---------------------------------------------------------------------------
__global__ __launch_bounds__(256) void gemm_kernel(
    const float* __restrict__ notes, const float* __restrict__ w,
    const int* __restrict__ g_ptr, float* __restrict__ x0,
    float* __restrict__ out, int n_nodes) {
  __shared__ float wlds[H * H];   // 64 KB
  __shared__ float nlds[16 * H];  // 8 KB
  const int tid = threadIdx.x;
  {
    const float4* w4 = (const float4*)w;
    float4* wl4 = (float4*)wlds;
    for (int i = tid; i < (H * H) / 4; i += 256) wl4[i] = w4[i];
  }
  const int rowBlk = blockIdx.x * 16;
  {
    float4* nl4 = (float4*)nlds;
    for (int i = tid; i < (16 * H) / 4; i += 256) {
      const int r = min(rowBlk + i / (H / 4), n_nodes - 1);
      const int c = i % (H / 4);
      nl4[i] = ((const float4*)(notes + (size_t)r * H))[c];
    }
  }
  __syncthreads();

  const int wave = tid >> 6;
  const int lane = tid & 63;
  const int g = *g_ptr;
  const int rowBase = rowBlk + wave * 4;
  if (rowBase >= n_nodes) return;

  const float* n0 = &nlds[(wave * 4 + 0) * H];
  const float* n1 = &nlds[(wave * 4 + 1) * H];
  const float* n2 = &nlds[(wave * 4 + 2) * H];
  const float* n3 = &nlds[(wave * 4 + 3) * H];

  float a00 = 0.f, a01 = 0.f, a10 = 0.f, a11 = 0.f;
  float a20 = 0.f, a21 = 0.f, a30 = 0.f, a31 = 0.f;
#pragma unroll 4
  for (int k = 0; k < H; ++k) {
    const float w0 = wlds[k * H + lane];
    const float w1 = wlds[k * H + lane + 64];
    const float v0 = n0[k];
    const float v1 = n1[k];
    const float v2 = n2[k];
    const float v3 = n3[k];
    a00 += v0 * w0; a01 += v0 * w1;
    a10 += v1 * w0; a11 += v1 * w1;
    a20 += v2 * w0; a21 += v2 * w1;
    a30 += v3 * w0; a31 += v3 * w1;
  }

  float lo[4] = {a00, a10, a20, a30};
  float hi[4] = {a01, a11, a21, a31};
#pragma unroll
  for (int i = 0; i < 4; ++i) {
    const int r = rowBase + i;
    if (r < n_nodes) {
      x0[(size_t)r * H + lane] = lo[i];
      x0[(size_t)r * H + lane + 64] = hi[i];
      if (r >= g) {
        const size_t o = (size_t)(n_nodes + r - g) * H;
        out[o + lane] = lo[i];
        out[o + lane + 64] = hi[i];
      }
    }
  }
}

// ---------------------------------------------------------------------------
// CSR build: histogram -> exclusive scan (3 kernels) -> fill.
// ---------------------------------------------------------------------------
__global__ __launch_bounds__(256) void hist_kernel(const int* __restrict__ esrc,
                                                   int* __restrict__ deg,
                                                   int n_edges) {
  int i = blockIdx.x * blockDim.x + threadIdx.x;
  const int stride = gridDim.x * blockDim.x;
  for (; i < n_edges; i += stride) atomicAdd(&deg[esrc[i]], 1);
}

__global__ __launch_bounds__(SCAN_B) void scan_reduce(const int* __restrict__ deg,
                                                      int* __restrict__ bsum,
                                                      int n) {
  __shared__ int s[SCAN_B];
  const int i = blockIdx.x * SCAN_B + threadIdx.x;
  s[threadIdx.x] = (i < n) ? deg[i] : 0;
  __syncthreads();
  for (int off = SCAN_B / 2; off > 0; off >>= 1) {
    if (threadIdx.x < off) s[threadIdx.x] += s[threadIdx.x + off];
    __syncthreads();
  }
  if (threadIdx.x == 0) bsum[blockIdx.x] = s[0];
}

// Single block: exclusive-scan bsum[0..nb) in place (nb <= 256), write total.
__global__ __launch_bounds__(256) void scan_bsum(int* __restrict__ bsum, int nb,
                                                 int* __restrict__ totalp) {
  __shared__ int s[256];
  const int t = threadIdx.x;
  const int v = (t < nb) ? bsum[t] : 0;
  s[t] = v;
  __syncthreads();
  for (int off = 1; off < 256; off <<= 1) {
    const int tv = (t >= off) ? s[t - off] : 0;
    __syncthreads();
    s[t] += tv;
    __syncthreads();
  }
  if (t < nb) bsum[t] = s[t] - v;  // exclusive
  if (t == 255) *totalp = s[255];
}

__global__ __launch_bounds__(SCAN_B) void scan_final(
    const int* __restrict__ deg, const int* __restrict__ bsum,
    const int* __restrict__ totalp, int* __restrict__ off,
    int* __restrict__ cursor, int n) {
  __shared__ int s[SCAN_B];
  const int t = threadIdx.x;
  const int i = blockIdx.x * SCAN_B + t;
  const int v = (i < n) ? deg[i] : 0;
  s[t] = v;
  __syncthreads();
  for (int o = 1; o < SCAN_B; o <<= 1) {
    const int tv = (t >= o) ? s[t - o] : 0;
    __syncthreads();
    s[t] += tv;
    __syncthreads();
  }
  const int excl = s[t] - v + bsum[blockIdx.x];
  if (i < n) {
    off[i] = excl;
    cursor[i] = excl;
  }
  if (blockIdx.x == 0 && t == 0) off[n] = *totalp;
}

__global__ __launch_bounds__(256) void fill_kernel(
    const int* __restrict__ esrc, const int* __restrict__ edst,
    const float* __restrict__ ew, int* __restrict__ cursor,
    int2* __restrict__ sedge, int n_edges) {
  int i = blockIdx.x * blockDim.x + threadIdx.x;
  const int stride = gridDim.x * blockDim.x;
  for (; i < n_edges; i += stride) {
    const int s = esrc[i];
    const int p = atomicAdd(&cursor[s], 1);
    int2 pk;
    pk.x = edst[i];
    pk.y = __float_as_int(ew[i]);
    sedge[p] = pk;
  }
}

// ---------------------------------------------------------------------------
// Gather: one wave per node. acc = sum_e w_e * X0[dst_e]; out = relu(acc + b).
// Each edge = one fully coalesced 512B row read; X0 is L3-resident.
// ---------------------------------------------------------------------------
__global__ __launch_bounds__(256) void gather_kernel(
    const int* __restrict__ off, const int2* __restrict__ sedge,
    const float* __restrict__ x0, const float* __restrict__ b,
    float* __restrict__ out, int n_nodes) {
  const int wave = blockIdx.x * (blockDim.x >> 6) + (threadIdx.x >> 6);
  const int lane = threadIdx.x & 63;
  if (wave >= n_nodes) return;
  const int beg = off[wave];
  const int end = off[wave + 1];
  const float2* __restrict__ x0v = (const float2*)x0;

  float2 a0 = {0.f, 0.f}, a1 = {0.f, 0.f};
  int e = beg;
  for (; e + 1 < end; e += 2) {
    const int2 e0 = sedge[e];
    const int2 e1 = sedge[e + 1];
    const float2 v0 = x0v[(size_t)e0.x * 64 + lane];
    const float2 v1 = x0v[(size_t)e1.x * 64 + lane];
    const float w0 = __int_as_float(e0.y);
    const float w1 = __int_as_float(e1.y);
    a0.x += v0.x * w0; a0.y += v0.y * w0;
    a1.x += v1.x * w1; a1.y += v1.y * w1;
  }
  if (e < end) {
    const int2 e0 = sedge[e];
    const float2 v0 = x0v[(size_t)e0.x * 64 + lane];
    const float w0 = __int_as_float(e0.y);
    a0.x += v0.x * w0; a0.y += v0.y * w0;
  }
  const float2 bb = ((const float2*)b)[lane];
  float2 r;
  r.x = fmaxf(a0.x + a1.x + bb.x, 0.f);
  r.y = fmaxf(a0.y + a1.y + bb.y, 0.f);
  ((float2*)out)[(size_t)wave * 64 + lane] = r;
}

// ---------------------------------------------------------------------------
// Fallback path (if ws too small for CSR): atomic scatter + epilogue.
// ---------------------------------------------------------------------------
__global__ __launch_bounds__(256) void scatter_kernel(
    const int* __restrict__ esrc, const int* __restrict__ edst,
    const float* __restrict__ ew, const float* __restrict__ x0,
    float* __restrict__ acc, int n_edges) {
  const int lane = threadIdx.x & 63;
  const int waveId = blockIdx.x * (blockDim.x >> 6) + (threadIdx.x >> 6);
  const int nWaves = gridDim.x * (blockDim.x >> 6);
  const float2* __restrict__ x0v = (const float2*)x0;
  for (int e = waveId; e < n_edges; e += nWaves) {
    const int s = esrc[e];
    const int d = edst[e];
    const float wt = ew[e];
    const float2 v = x0v[(size_t)d * 64 + lane];
    float* p = acc + (size_t)s * H + lane * 2;
    atomicAdd(p, v.x * wt);
    atomicAdd(p + 1, v.y * wt);
  }
}

__global__ __launch_bounds__(256) void epilogue_kernel(
    float* __restrict__ out, const float* __restrict__ b, int n4) {
  const int i = blockIdx.x * blockDim.x + threadIdx.x;
  if (i >= n4) return;
  float4* o4 = (float4*)out;
  const float4* b4 = (const float4*)b;
  float4 v = o4[i];
  const float4 bb = b4[i & 31];
  v.x = fmaxf(v.x + bb.x, 0.f);
  v.y = fmaxf(v.y + bb.y, 0.f);
  v.z = fmaxf(v.z + bb.z, 0.f);
  v.w = fmaxf(v.w + bb.w, 0.f);
  o4[i] = v;
}

extern "C" void kernel_launch(void* const* d_in, const int* in_sizes, int n_in,
                              void* d_out, int out_size, void* d_ws, size_t ws_size,
                              hipStream_t stream) {
  const float* notes = (const float*)d_in[0];
  const float* w     = (const float*)d_in[1];
  const float* b     = (const float*)d_in[2];
  const int*   esrc  = (const int*)d_in[3];
  const int*   edst  = (const int*)d_in[4];
  const float* ew    = (const float*)d_in[5];
  const int*   gptr  = (const int*)d_in[6];

  const int n_nodes = in_sizes[0] / H;
  const int n_edges = in_sizes[3];
  float* out = (float*)d_out;

  // Workspace carve-up (256B-aligned regions).
  char* ws = (char*)d_ws;
  size_t p = 0;
  auto alloc = [&](size_t bytes) -> char* {
    char* cur = ws + p;
    p = (p + bytes + 255) & ~(size_t)255;
    return cur;
  };
  float* x0    = (float*)alloc((size_t)n_nodes * H * sizeof(float));
  int*   deg   = (int*)alloc((size_t)n_nodes * sizeof(int));
  int*   off   = (int*)alloc(((size_t)n_nodes + 1) * sizeof(int));
  int*   cur   = (int*)alloc((size_t)n_nodes * sizeof(int));
  int*   bsum  = (int*)alloc(256 * sizeof(int));
  int*   totalp = (int*)alloc(sizeof(int));
  int2*  sedge = (int2*)alloc((size_t)n_edges * sizeof(int2));
  const bool csr_ok = (p <= ws_size) && (((n_nodes + SCAN_B - 1) / SCAN_B) <= 256);

  // GEMM (also writes concat tail rows).
  gemm_kernel<<<(n_nodes + 15) / 16, 256, 0, stream>>>(notes, w, gptr, x0, out,
                                                       n_nodes);

  if (csr_ok) {
    hipMemsetAsync(deg, 0, (size_t)n_nodes * sizeof(int), stream);
    hist_kernel<<<2048, 256, 0, stream>>>(esrc, deg, n_edges);
    const int nb = (n_nodes + SCAN_B - 1) / SCAN_B;
    scan_reduce<<<nb, SCAN_B, 0, stream>>>(deg, bsum, n_nodes);
    scan_bsum<<<1, 256, 0, stream>>>(bsum, nb, totalp);
    scan_final<<<nb, SCAN_B, 0, stream>>>(deg, bsum, totalp, off, cur, n_nodes);
    fill_kernel<<<2048, 256, 0, stream>>>(esrc, edst, ew, cur, sedge, n_edges);
    gather_kernel<<<(n_nodes + 3) / 4, 256, 0, stream>>>(off, sedge, x0, b, out,
                                                         n_nodes);
  } else {
    hipMemsetAsync(d_out, 0, (size_t)n_nodes * H * sizeof(float), stream);
    scatter_kernel<<<2048, 256, 0, stream>>>(esrc, edst, ew, x0, out, n_edges);
    const int n4 = n_nodes * H / 4;
    epilogue_kernel<<<(n4 + 255) / 256, 256, 0, stream>>>(out, b, n4);
  }
}

// Round 3
// 511.778 us; speedup vs baseline: 3.1113x; 1.0350x over previous
//
#include <hip/hip_runtime.h>

#define H 128
#define SCAN_B 512

// ---------------------------------------------------------------------------
// GEMM: X0 = notes @ w. w (64KB) + 16 note-rows (8KB) staged in LDS.
// Each wave: 4 rows; each lane: cols (lane, lane+64).
// Rows >= garment_size also written straight to the output tail (concat pt 2).
// ---------------------------------------------------------------------------
__global__ __launch_bounds__(256) void gemm_kernel(
    const float* __restrict__ notes, const float* __restrict__ w,
    const int* __restrict__ g_ptr, float* __restrict__ x0,
    float* __restrict__ out, int n_nodes) {
  __shared__ float wlds[H * H];   // 64 KB
  __shared__ float nlds[16 * H];  // 8 KB
  const int tid = threadIdx.x;
  {
    const float4* w4 = (const float4*)w;
    float4* wl4 = (float4*)wlds;
    for (int i = tid; i < (H * H) / 4; i += 256) wl4[i] = w4[i];
  }
  const int rowBlk = blockIdx.x * 16;
  {
    float4* nl4 = (float4*)nlds;
    for (int i = tid; i < (16 * H) / 4; i += 256) {
      const int r = min(rowBlk + i / (H / 4), n_nodes - 1);
      const int c = i % (H / 4);
      nl4[i] = ((const float4*)(notes + (size_t)r * H))[c];
    }
  }
  __syncthreads();

  const int wave = tid >> 6;
  const int lane = tid & 63;
  const int g = *g_ptr;
  const int rowBase = rowBlk + wave * 4;
  if (rowBase >= n_nodes) return;

  const float* n0 = &nlds[(wave * 4 + 0) * H];
  const float* n1 = &nlds[(wave * 4 + 1) * H];
  const float* n2 = &nlds[(wave * 4 + 2) * H];
  const float* n3 = &nlds[(wave * 4 + 3) * H];

  float a00 = 0.f, a01 = 0.f, a10 = 0.f, a11 = 0.f;
  float a20 = 0.f, a21 = 0.f, a30 = 0.f, a31 = 0.f;
#pragma unroll 4
  for (int k = 0; k < H; ++k) {
    const float w0 = wlds[k * H + lane];
    const float w1 = wlds[k * H + lane + 64];
    const float v0 = n0[k];
    const float v1 = n1[k];
    const float v2 = n2[k];
    const float v3 = n3[k];
    a00 += v0 * w0; a01 += v0 * w1;
    a10 += v1 * w0; a11 += v1 * w1;
    a20 += v2 * w0; a21 += v2 * w1;
    a30 += v3 * w0; a31 += v3 * w1;
  }

  float lo[4] = {a00, a10, a20, a30};
  float hi[4] = {a01, a11, a21, a31};
#pragma unroll
  for (int i = 0; i < 4; ++i) {
    const int r = rowBase + i;
    if (r < n_nodes) {
      x0[(size_t)r * H + lane] = lo[i];
      x0[(size_t)r * H + lane + 64] = hi[i];
      if (r >= g) {
        const size_t o = (size_t)(n_nodes + r - g) * H;
        out[o + lane] = lo[i];
        out[o + lane + 64] = hi[i];
      }
    }
  }
}

// ---------------------------------------------------------------------------
// CSR build: histogram -> exclusive scan (3 kernels) -> fill.
// ---------------------------------------------------------------------------
__global__ __launch_bounds__(256) void hist_kernel(const int* __restrict__ esrc,
                                                   int* __restrict__ deg,
                                                   int n_edges) {
  int i = blockIdx.x * blockDim.x + threadIdx.x;
  const int stride = gridDim.x * blockDim.x;
  for (; i < n_edges; i += stride) atomicAdd(&deg[esrc[i]], 1);
}

__global__ __launch_bounds__(SCAN_B) void scan_reduce(const int* __restrict__ deg,
                                                      int* __restrict__ bsum,
                                                      int n) {
  __shared__ int s[SCAN_B];
  const int i = blockIdx.x * SCAN_B + threadIdx.x;
  s[threadIdx.x] = (i < n) ? deg[i] : 0;
  __syncthreads();
  for (int off = SCAN_B / 2; off > 0; off >>= 1) {
    if (threadIdx.x < off) s[threadIdx.x] += s[threadIdx.x + off];
    __syncthreads();
  }
  if (threadIdx.x == 0) bsum[blockIdx.x] = s[0];
}

// Single block: exclusive-scan bsum[0..nb) in place (nb <= 256), write total.
__global__ __launch_bounds__(256) void scan_bsum(int* __restrict__ bsum, int nb,
                                                 int* __restrict__ totalp) {
  __shared__ int s[256];
  const int t = threadIdx.x;
  const int v = (t < nb) ? bsum[t] : 0;
  s[t] = v;
  __syncthreads();
  for (int off = 1; off < 256; off <<= 1) {
    const int tv = (t >= off) ? s[t - off] : 0;
    __syncthreads();
    s[t] += tv;
    __syncthreads();
  }
  if (t < nb) bsum[t] = s[t] - v;  // exclusive
  if (t == 255) *totalp = s[255];
}

__global__ __launch_bounds__(SCAN_B) void scan_final(
    const int* __restrict__ deg, const int* __restrict__ bsum,
    const int* __restrict__ totalp, int* __restrict__ off,
    int* __restrict__ cursor, int n) {
  __shared__ int s[SCAN_B];
  const int t = threadIdx.x;
  const int i = blockIdx.x * SCAN_B + t;
  const int v = (i < n) ? deg[i] : 0;
  s[t] = v;
  __syncthreads();
  for (int o = 1; o < SCAN_B; o <<= 1) {
    const int tv = (t >= o) ? s[t - o] : 0;
    __syncthreads();
    s[t] += tv;
    __syncthreads();
  }
  const int excl = s[t] - v + bsum[blockIdx.x];
  if (i < n) {
    off[i] = excl;
    cursor[i] = excl;
  }
  if (blockIdx.x == 0 && t == 0) off[n] = *totalp;
}

// ---------------------------------------------------------------------------
// Fill: batched phases to keep 8 atomic round-trips in flight per thread.
// Block b owns edges [b*2048, b*2048+2048); thread t handles k*256+t.
// ---------------------------------------------------------------------------
__global__ __launch_bounds__(256) void fill_kernel(
    const int* __restrict__ esrc, const int* __restrict__ edst,
    const float* __restrict__ ew, int* __restrict__ cursor,
    int2* __restrict__ sedge, int n_edges) {
  const int chunk = blockIdx.x * 2048;
  int s[8];
  int2 pk[8];
  bool valid[8];
#pragma unroll
  for (int k = 0; k < 8; ++k) {
    const int e = chunk + k * 256 + threadIdx.x;
    valid[k] = e < n_edges;
    const int ee = valid[k] ? e : 0;
    s[k] = esrc[ee];
    pk[k].x = edst[ee];
    pk[k].y = __float_as_int(ew[ee]);
  }
  int pos[8];
#pragma unroll
  for (int k = 0; k < 8; ++k) {
    if (valid[k]) pos[k] = atomicAdd(&cursor[s[k]], 1);
  }
#pragma unroll
  for (int k = 0; k < 8; ++k) {
    if (valid[k]) sedge[pos[k]] = pk[k];
  }
}

// ---------------------------------------------------------------------------
// Gather: one wave per node. acc = sum_e w_e * X0[dst_e]; out = relu(acc + b).
// 4 independent 512B row-loads in flight per wave to hide L3 latency.
// ---------------------------------------------------------------------------
__global__ __launch_bounds__(256) void gather_kernel(
    const int* __restrict__ off, const int2* __restrict__ sedge,
    const float* __restrict__ x0, const float* __restrict__ b,
    float* __restrict__ out, int n_nodes) {
  const int wave = blockIdx.x * (blockDim.x >> 6) + (threadIdx.x >> 6);
  const int lane = threadIdx.x & 63;
  if (wave >= n_nodes) return;
  const int beg = off[wave];
  const int end = off[wave + 1];
  const float2* __restrict__ x0v = (const float2*)x0;

  float2 a0 = {0.f, 0.f}, a1 = {0.f, 0.f};
  float2 a2 = {0.f, 0.f}, a3 = {0.f, 0.f};
  int e = beg;
  for (; e + 3 < end; e += 4) {
    const int2 e0 = sedge[e];
    const int2 e1 = sedge[e + 1];
    const int2 e2 = sedge[e + 2];
    const int2 e3 = sedge[e + 3];
    const float2 v0 = x0v[(size_t)e0.x * 64 + lane];
    const float2 v1 = x0v[(size_t)e1.x * 64 + lane];
    const float2 v2 = x0v[(size_t)e2.x * 64 + lane];
    const float2 v3 = x0v[(size_t)e3.x * 64 + lane];
    const float w0 = __int_as_float(e0.y);
    const float w1 = __int_as_float(e1.y);
    const float w2 = __int_as_float(e2.y);
    const float w3 = __int_as_float(e3.y);
    a0.x += v0.x * w0; a0.y += v0.y * w0;
    a1.x += v1.x * w1; a1.y += v1.y * w1;
    a2.x += v2.x * w2; a2.y += v2.y * w2;
    a3.x += v3.x * w3; a3.y += v3.y * w3;
  }
  for (; e < end; ++e) {
    const int2 e0 = sedge[e];
    const float2 v0 = x0v[(size_t)e0.x * 64 + lane];
    const float w0 = __int_as_float(e0.y);
    a0.x += v0.x * w0; a0.y += v0.y * w0;
  }
  const float2 bb = ((const float2*)b)[lane];
  float2 r;
  r.x = fmaxf(a0.x + a1.x + a2.x + a3.x + bb.x, 0.f);
  r.y = fmaxf(a0.y + a1.y + a2.y + a3.y + bb.y, 0.f);
  ((float2*)out)[(size_t)wave * 64 + lane] = r;
}

// ---------------------------------------------------------------------------
// Fallback path (if ws too small for CSR): atomic scatter + epilogue.
// ---------------------------------------------------------------------------
__global__ __launch_bounds__(256) void scatter_kernel(
    const int* __restrict__ esrc, const int* __restrict__ edst,
    const float* __restrict__ ew, const float* __restrict__ x0,
    float* __restrict__ acc, int n_edges) {
  const int lane = threadIdx.x & 63;
  const int waveId = blockIdx.x * (blockDim.x >> 6) + (threadIdx.x >> 6);
  const int nWaves = gridDim.x * (blockDim.x >> 6);
  const float2* __restrict__ x0v = (const float2*)x0;
  for (int e = waveId; e < n_edges; e += nWaves) {
    const int s = esrc[e];
    const int d = edst[e];
    const float wt = ew[e];
    const float2 v = x0v[(size_t)d * 64 + lane];
    float* p = acc + (size_t)s * H + lane * 2;
    atomicAdd(p, v.x * wt);
    atomicAdd(p + 1, v.y * wt);
  }
}

__global__ __launch_bounds__(256) void epilogue_kernel(
    float* __restrict__ out, const float* __restrict__ b, int n4) {
  const int i = blockIdx.x * blockDim.x + threadIdx.x;
  if (i >= n4) return;
  float4* o4 = (float4*)out;
  const float4* b4 = (const float4*)b;
  float4 v = o4[i];
  const float4 bb = b4[i & 31];
  v.x = fmaxf(v.x + bb.x, 0.f);
  v.y = fmaxf(v.y + bb.y, 0.f);
  v.z = fmaxf(v.z + bb.z, 0.f);
  v.w = fmaxf(v.w + bb.w, 0.f);
  o4[i] = v;
}

extern "C" void kernel_launch(void* const* d_in, const int* in_sizes, int n_in,
                              void* d_out, int out_size, void* d_ws, size_t ws_size,
                              hipStream_t stream) {
  const float* notes = (const float*)d_in[0];
  const float* w     = (const float*)d_in[1];
  const float* b     = (const float*)d_in[2];
  const int*   esrc  = (const int*)d_in[3];
  const int*   edst  = (const int*)d_in[4];
  const float* ew    = (const float*)d_in[5];
  const int*   gptr  = (const int*)d_in[6];

  const int n_nodes = in_sizes[0] / H;
  const int n_edges = in_sizes[3];
  float* out = (float*)d_out;

  // Workspace carve-up (256B-aligned regions).
  char* ws = (char*)d_ws;
  size_t p = 0;
  auto alloc = [&](size_t bytes) -> char* {
    char* cur = ws + p;
    p = (p + bytes + 255) & ~(size_t)255;
    return cur;
  };
  float* x0    = (float*)alloc((size_t)n_nodes * H * sizeof(float));
  int*   deg   = (int*)alloc((size_t)n_nodes * sizeof(int));
  int*   off   = (int*)alloc(((size_t)n_nodes + 1) * sizeof(int));
  int*   cur   = (int*)alloc((size_t)n_nodes * sizeof(int));
  int*   bsum  = (int*)alloc(256 * sizeof(int));
  int*   totalp = (int*)alloc(sizeof(int));
  int2*  sedge = (int2*)alloc((size_t)n_edges * sizeof(int2));
  const bool csr_ok = (p <= ws_size) && (((n_nodes + SCAN_B - 1) / SCAN_B) <= 256);

  // GEMM (also writes concat tail rows).
  gemm_kernel<<<(n_nodes + 15) / 16, 256, 0, stream>>>(notes, w, gptr, x0, out,
                                                       n_nodes);

  if (csr_ok) {
    hipMemsetAsync(deg, 0, (size_t)n_nodes * sizeof(int), stream);
    hist_kernel<<<2048, 256, 0, stream>>>(esrc, deg, n_edges);
    const int nb = (n_nodes + SCAN_B - 1) / SCAN_B;
    scan_reduce<<<nb, SCAN_B, 0, stream>>>(deg, bsum, n_nodes);
    scan_bsum<<<1, 256, 0, stream>>>(bsum, nb, totalp);
    scan_final<<<nb, SCAN_B, 0, stream>>>(deg, bsum, totalp, off, cur, n_nodes);
    fill_kernel<<<(n_edges + 2047) / 2048, 256, 0, stream>>>(esrc, edst, ew,
                                                             cur, sedge,
                                                             n_edges);
    gather_kernel<<<(n_nodes + 3) / 4, 256, 0, stream>>>(off, sedge, x0, b, out,
                                                         n_nodes);
  } else {
    hipMemsetAsync(d_out, 0, (size_t)n_nodes * H * sizeof(float), stream);
    scatter_kernel<<<2048, 256, 0, stream>>>(esrc, edst, ew, x0, out, n_edges);
    const int n4 = n_nodes * H / 4;
    epilogue_kernel<<<(n4 + 255) / 256, 256, 0, stream>>>(out, b, n4);
  }
}

// Round 4
// 445.344 us; speedup vs baseline: 3.5754x; 1.1492x over previous
//
#include <hip/hip_runtime.h>

#define H 128
#define SCAN_B 512

// ---------------------------------------------------------------------------
// GEMM: X0 = notes @ w, register-blocked.
// Block tile: 64 rows x 128 cols; k staged in chunks of 32.
// Thread (tx=t&31, ty=t>>5) owns rows ty*8..+7, cols tx*4..+3 (8x4 acc).
// Per k: 1 ds_read_b128 (w) + 8 broadcast ds_read_b32 (notes) -> 32 FMA.
// LDS 24KB -> 6 blocks/CU. Rows >= garment also written to output tail.
// ---------------------------------------------------------------------------
__global__ __launch_bounds__(256) void gemm_kernel(
    const float* __restrict__ notes, const float* __restrict__ w,
    const int* __restrict__ g_ptr, float* __restrict__ x0,
    float* __restrict__ out, int n_nodes) {
  __shared__ float wtile[32 * H];   // 16 KB: w[kc+kk][c]
  __shared__ float ntile[64 * 32];  // 8 KB:  notes[row][kk]
  const int tid = threadIdx.x;
  const int tx = tid & 31;
  const int ty = tid >> 5;
  const int rowBlk = blockIdx.x * 64;
  const int g = *g_ptr;

  float acc[8][4];
#pragma unroll
  for (int i = 0; i < 8; ++i)
#pragma unroll
    for (int j = 0; j < 4; ++j) acc[i][j] = 0.f;

  for (int kc = 0; kc < H; kc += 32) {
    __syncthreads();  // protect previous chunk's LDS reads
    // Stage w[kc..kc+31][0..127]: 1024 float4, 4 per thread, stride-1.
    {
      const float4* wg = (const float4*)(w + (size_t)kc * H);
      float4* wl = (float4*)wtile;
#pragma unroll
      for (int i = 0; i < 4; ++i) wl[tid + i * 256] = wg[tid + i * 256];
    }
    // Stage notes[rowBlk..+63][kc..kc+31]: 512 float4, 2 per thread.
    {
      float4* nl = (float4*)ntile;
#pragma unroll
      for (int i = 0; i < 2; ++i) {
        const int idx = tid + i * 256;
        const int row = idx >> 3;
        const int q = idx & 7;
        const int rr = min(rowBlk + row, n_nodes - 1);
        nl[idx] = *(const float4*)(notes + (size_t)rr * H + kc + q * 4);
      }
    }
    __syncthreads();
#pragma unroll 8
    for (int kk = 0; kk < 32; ++kk) {
      const float4 b4 = *(const float4*)&wtile[kk * H + tx * 4];
      float a[8];
#pragma unroll
      for (int i = 0; i < 8; ++i) a[i] = ntile[(ty * 8 + i) * 32 + kk];
#pragma unroll
      for (int i = 0; i < 8; ++i) {
        acc[i][0] += a[i] * b4.x;
        acc[i][1] += a[i] * b4.y;
        acc[i][2] += a[i] * b4.z;
        acc[i][3] += a[i] * b4.w;
      }
    }
  }

#pragma unroll
  for (int i = 0; i < 8; ++i) {
    const int r = rowBlk + ty * 8 + i;
    if (r < n_nodes) {
      float4 v;
      v.x = acc[i][0]; v.y = acc[i][1]; v.z = acc[i][2]; v.w = acc[i][3];
      *(float4*)(x0 + (size_t)r * H + tx * 4) = v;
      if (r >= g) {
        *(float4*)(out + (size_t)(n_nodes + r - g) * H + tx * 4) = v;
      }
    }
  }
}

// ---------------------------------------------------------------------------
// CSR build: histogram -> exclusive scan (3 kernels) -> fill.
// ---------------------------------------------------------------------------
__global__ __launch_bounds__(256) void hist_kernel(const int* __restrict__ esrc,
                                                   int* __restrict__ deg,
                                                   int n_edges) {
  int i = blockIdx.x * blockDim.x + threadIdx.x;
  const int stride = gridDim.x * blockDim.x;
  for (; i < n_edges; i += stride) atomicAdd(&deg[esrc[i]], 1);
}

__global__ __launch_bounds__(SCAN_B) void scan_reduce(const int* __restrict__ deg,
                                                      int* __restrict__ bsum,
                                                      int n) {
  __shared__ int s[SCAN_B];
  const int i = blockIdx.x * SCAN_B + threadIdx.x;
  s[threadIdx.x] = (i < n) ? deg[i] : 0;
  __syncthreads();
  for (int off = SCAN_B / 2; off > 0; off >>= 1) {
    if (threadIdx.x < off) s[threadIdx.x] += s[threadIdx.x + off];
    __syncthreads();
  }
  if (threadIdx.x == 0) bsum[blockIdx.x] = s[0];
}

// Single block: exclusive-scan bsum[0..nb) in place (nb <= 256), write total.
__global__ __launch_bounds__(256) void scan_bsum(int* __restrict__ bsum, int nb,
                                                 int* __restrict__ totalp) {
  __shared__ int s[256];
  const int t = threadIdx.x;
  const int v = (t < nb) ? bsum[t] : 0;
  s[t] = v;
  __syncthreads();
  for (int off = 1; off < 256; off <<= 1) {
    const int tv = (t >= off) ? s[t - off] : 0;
    __syncthreads();
    s[t] += tv;
    __syncthreads();
  }
  if (t < nb) bsum[t] = s[t] - v;  // exclusive
  if (t == 255) *totalp = s[255];
}

__global__ __launch_bounds__(SCAN_B) void scan_final(
    const int* __restrict__ deg, const int* __restrict__ bsum,
    const int* __restrict__ totalp, int* __restrict__ off,
    int* __restrict__ cursor, int n) {
  __shared__ int s[SCAN_B];
  const int t = threadIdx.x;
  const int i = blockIdx.x * SCAN_B + t;
  const int v = (i < n) ? deg[i] : 0;
  s[t] = v;
  __syncthreads();
  for (int o = 1; o < SCAN_B; o <<= 1) {
    const int tv = (t >= o) ? s[t - o] : 0;
    __syncthreads();
    s[t] += tv;
    __syncthreads();
  }
  const int excl = s[t] - v + bsum[blockIdx.x];
  if (i < n) {
    off[i] = excl;
    cursor[i] = excl;
  }
  if (blockIdx.x == 0 && t == 0) off[n] = *totalp;
}

// ---------------------------------------------------------------------------
// Fill: batched phases to keep 8 atomic round-trips in flight per thread.
// ---------------------------------------------------------------------------
__global__ __launch_bounds__(256) void fill_kernel(
    const int* __restrict__ esrc, const int* __restrict__ edst,
    const float* __restrict__ ew, int* __restrict__ cursor,
    int2* __restrict__ sedge, int n_edges) {
  const int chunk = blockIdx.x * 2048;
  int s[8];
  int2 pk[8];
  bool valid[8];
#pragma unroll
  for (int k = 0; k < 8; ++k) {
    const int e = chunk + k * 256 + threadIdx.x;
    valid[k] = e < n_edges;
    const int ee = valid[k] ? e : 0;
    s[k] = esrc[ee];
    pk[k].x = edst[ee];
    pk[k].y = __float_as_int(ew[ee]);
  }
  int pos[8];
#pragma unroll
  for (int k = 0; k < 8; ++k) {
    if (valid[k]) pos[k] = atomicAdd(&cursor[s[k]], 1);
  }
#pragma unroll
  for (int k = 0; k < 8; ++k) {
    if (valid[k]) sedge[pos[k]] = pk[k];
  }
}

// ---------------------------------------------------------------------------
// Gather: one wave per node. acc = sum_e w_e * X0[dst_e]; out = relu(acc + b).
// 4 independent 512B row-loads in flight per wave to hide L3 latency.
// ---------------------------------------------------------------------------
__global__ __launch_bounds__(256) void gather_kernel(
    const int* __restrict__ off, const int2* __restrict__ sedge,
    const float* __restrict__ x0, const float* __restrict__ b,
    float* __restrict__ out, int n_nodes) {
  const int wave = blockIdx.x * (blockDim.x >> 6) + (threadIdx.x >> 6);
  const int lane = threadIdx.x & 63;
  if (wave >= n_nodes) return;
  const int beg = off[wave];
  const int end = off[wave + 1];
  const float2* __restrict__ x0v = (const float2*)x0;

  float2 a0 = {0.f, 0.f}, a1 = {0.f, 0.f};
  float2 a2 = {0.f, 0.f}, a3 = {0.f, 0.f};
  int e = beg;
  for (; e + 3 < end; e += 4) {
    const int2 e0 = sedge[e];
    const int2 e1 = sedge[e + 1];
    const int2 e2 = sedge[e + 2];
    const int2 e3 = sedge[e + 3];
    const float2 v0 = x0v[(size_t)e0.x * 64 + lane];
    const float2 v1 = x0v[(size_t)e1.x * 64 + lane];
    const float2 v2 = x0v[(size_t)e2.x * 64 + lane];
    const float2 v3 = x0v[(size_t)e3.x * 64 + lane];
    const float w0 = __int_as_float(e0.y);
    const float w1 = __int_as_float(e1.y);
    const float w2 = __int_as_float(e2.y);
    const float w3 = __int_as_float(e3.y);
    a0.x += v0.x * w0; a0.y += v0.y * w0;
    a1.x += v1.x * w1; a1.y += v1.y * w1;
    a2.x += v2.x * w2; a2.y += v2.y * w2;
    a3.x += v3.x * w3; a3.y += v3.y * w3;
  }
  for (; e < end; ++e) {
    const int2 e0 = sedge[e];
    const float2 v0 = x0v[(size_t)e0.x * 64 + lane];
    const float w0 = __int_as_float(e0.y);
    a0.x += v0.x * w0; a0.y += v0.y * w0;
  }
  const float2 bb = ((const float2*)b)[lane];
  float2 r;
  r.x = fmaxf(a0.x + a1.x + a2.x + a3.x + bb.x, 0.f);
  r.y = fmaxf(a0.y + a1.y + a2.y + a3.y + bb.y, 0.f);
  ((float2*)out)[(size_t)wave * 64 + lane] = r;
}

// ---------------------------------------------------------------------------
// Fallback path (if ws too small for CSR): atomic scatter + epilogue.
// ---------------------------------------------------------------------------
__global__ __launch_bounds__(256) void scatter_kernel(
    const int* __restrict__ esrc, const int* __restrict__ edst,
    const float* __restrict__ ew, const float* __restrict__ x0,
    float* __restrict__ acc, int n_edges) {
  const int lane = threadIdx.x & 63;
  const int waveId = blockIdx.x * (blockDim.x >> 6) + (threadIdx.x >> 6);
  const int nWaves = gridDim.x * (blockDim.x >> 6);
  const float2* __restrict__ x0v = (const float2*)x0;
  for (int e = waveId; e < n_edges; e += nWaves) {
    const int s = esrc[e];
    const int d = edst[e];
    const float wt = ew[e];
    const float2 v = x0v[(size_t)d * 64 + lane];
    float* p = acc + (size_t)s * H + lane * 2;
    atomicAdd(p, v.x * wt);
    atomicAdd(p + 1, v.y * wt);
  }
}

__global__ __launch_bounds__(256) void epilogue_kernel(
    float* __restrict__ out, const float* __restrict__ b, int n4) {
  const int i = blockIdx.x * blockDim.x + threadIdx.x;
  if (i >= n4) return;
  float4* o4 = (float4*)out;
  const float4* b4 = (const float4*)b;
  float4 v = o4[i];
  const float4 bb = b4[i & 31];
  v.x = fmaxf(v.x + bb.x, 0.f);
  v.y = fmaxf(v.y + bb.y, 0.f);
  v.z = fmaxf(v.z + bb.z, 0.f);
  v.w = fmaxf(v.w + bb.w, 0.f);
  o4[i] = v;
}

extern "C" void kernel_launch(void* const* d_in, const int* in_sizes, int n_in,
                              void* d_out, int out_size, void* d_ws, size_t ws_size,
                              hipStream_t stream) {
  const float* notes = (const float*)d_in[0];
  const float* w     = (const float*)d_in[1];
  const float* b     = (const float*)d_in[2];
  const int*   esrc  = (const int*)d_in[3];
  const int*   edst  = (const int*)d_in[4];
  const float* ew    = (const float*)d_in[5];
  const int*   gptr  = (const int*)d_in[6];

  const int n_nodes = in_sizes[0] / H;
  const int n_edges = in_sizes[3];
  float* out = (float*)d_out;

  // Workspace carve-up (256B-aligned regions).
  char* ws = (char*)d_ws;
  size_t p = 0;
  auto alloc = [&](size_t bytes) -> char* {
    char* cur = ws + p;
    p = (p + bytes + 255) & ~(size_t)255;
    return cur;
  };
  float* x0    = (float*)alloc((size_t)n_nodes * H * sizeof(float));
  int*   deg   = (int*)alloc((size_t)n_nodes * sizeof(int));
  int*   off   = (int*)alloc(((size_t)n_nodes + 1) * sizeof(int));
  int*   cur   = (int*)alloc((size_t)n_nodes * sizeof(int));
  int*   bsum  = (int*)alloc(256 * sizeof(int));
  int*   totalp = (int*)alloc(sizeof(int));
  int2*  sedge = (int2*)alloc((size_t)n_edges * sizeof(int2));
  const bool csr_ok = (p <= ws_size) && (((n_nodes + SCAN_B - 1) / SCAN_B) <= 256);

  // GEMM (also writes concat tail rows).
  gemm_kernel<<<(n_nodes + 63) / 64, 256, 0, stream>>>(notes, w, gptr, x0, out,
                                                       n_nodes);

  if (csr_ok) {
    hipMemsetAsync(deg, 0, (size_t)n_nodes * sizeof(int), stream);
    hist_kernel<<<2048, 256, 0, stream>>>(esrc, deg, n_edges);
    const int nb = (n_nodes + SCAN_B - 1) / SCAN_B;
    scan_reduce<<<nb, SCAN_B, 0, stream>>>(deg, bsum, n_nodes);
    scan_bsum<<<1, 256, 0, stream>>>(bsum, nb, totalp);
    scan_final<<<nb, SCAN_B, 0, stream>>>(deg, bsum, totalp, off, cur, n_nodes);
    fill_kernel<<<(n_edges + 2047) / 2048, 256, 0, stream>>>(esrc, edst, ew,
                                                             cur, sedge,
                                                             n_edges);
    gather_kernel<<<(n_nodes + 3) / 4, 256, 0, stream>>>(off, sedge, x0, b, out,
                                                         n_nodes);
  } else {
    hipMemsetAsync(d_out, 0, (size_t)n_nodes * H * sizeof(float), stream);
    scatter_kernel<<<2048, 256, 0, stream>>>(esrc, edst, ew, x0, out, n_edges);
    const int n4 = n_nodes * H / 4;
    epilogue_kernel<<<(n4 + 255) / 256, 256, 0, stream>>>(out, b, n4);
  }
}

// Round 6
// 395.978 us; speedup vs baseline: 4.0211x; 1.1247x over previous
//
#include <hip/hip_runtime.h>

#define H 128
#define SCAN_B 512

// fp32 -> bf16 round-to-nearest-even
static __device__ __forceinline__ unsigned short f2bf(float f) {
  unsigned u = __float_as_uint(f);
  u += 0x7FFFu + ((u >> 16) & 1u);
  return (unsigned short)(u >> 16);
}

// ---------------------------------------------------------------------------
// GEMM: X0 = notes @ w, register-blocked.
// Block tile: 64 rows x 128 cols; k staged in chunks of 32.
// Thread (tx=t&31, ty=t>>5) owns rows ty*8..+7, cols tx*4..+3 (8x4 acc).
// x0 stored bf16 (gather consumes it); rows >= garment written fp32 straight
// to the output tail (concat part 2).
// ---------------------------------------------------------------------------
__global__ __launch_bounds__(256) void gemm_kernel(
    const float* __restrict__ notes, const float* __restrict__ w,
    const int* __restrict__ g_ptr, unsigned short* __restrict__ x0h,
    float* __restrict__ out, int n_nodes) {
  __shared__ float wtile[32 * H];   // 16 KB: w[kc+kk][c]
  __shared__ float ntile[64 * 32];  // 8 KB:  notes[row][kk]
  const int tid = threadIdx.x;
  const int tx = tid & 31;
  const int ty = tid >> 5;
  const int rowBlk = blockIdx.x * 64;
  const int g = *g_ptr;

  float acc[8][4];
#pragma unroll
  for (int i = 0; i < 8; ++i)
#pragma unroll
    for (int j = 0; j < 4; ++j) acc[i][j] = 0.f;

  for (int kc = 0; kc < H; kc += 32) {
    __syncthreads();  // protect previous chunk's LDS reads
    {
      const float4* wg = (const float4*)(w + (size_t)kc * H);
      float4* wl = (float4*)wtile;
#pragma unroll
      for (int i = 0; i < 4; ++i) wl[tid + i * 256] = wg[tid + i * 256];
    }
    {
      float4* nl = (float4*)ntile;
#pragma unroll
      for (int i = 0; i < 2; ++i) {
        const int idx = tid + i * 256;
        const int row = idx >> 3;
        const int q = idx & 7;
        const int rr = min(rowBlk + row, n_nodes - 1);
        nl[idx] = *(const float4*)(notes + (size_t)rr * H + kc + q * 4);
      }
    }
    __syncthreads();
#pragma unroll 8
    for (int kk = 0; kk < 32; ++kk) {
      const float4 b4 = *(const float4*)&wtile[kk * H + tx * 4];
      float a[8];
#pragma unroll
      for (int i = 0; i < 8; ++i) a[i] = ntile[(ty * 8 + i) * 32 + kk];
#pragma unroll
      for (int i = 0; i < 8; ++i) {
        acc[i][0] += a[i] * b4.x;
        acc[i][1] += a[i] * b4.y;
        acc[i][2] += a[i] * b4.z;
        acc[i][3] += a[i] * b4.w;
      }
    }
  }

#pragma unroll
  for (int i = 0; i < 8; ++i) {
    const int r = rowBlk + ty * 8 + i;
    if (r < n_nodes) {
      ushort4 h;
      h.x = f2bf(acc[i][0]);
      h.y = f2bf(acc[i][1]);
      h.z = f2bf(acc[i][2]);
      h.w = f2bf(acc[i][3]);
      *(ushort4*)(x0h + (size_t)r * H + tx * 4) = h;
      if (r >= g) {
        float4 v;
        v.x = acc[i][0]; v.y = acc[i][1]; v.z = acc[i][2]; v.w = acc[i][3];
        *(float4*)(out + (size_t)(n_nodes + r - g) * H + tx * 4) = v;
      }
    }
  }
}

// ---------------------------------------------------------------------------
// CSR build: histogram -> exclusive scan (3 kernels, R4-proven) -> fill.
// ---------------------------------------------------------------------------
__global__ __launch_bounds__(256) void hist_kernel(const int* __restrict__ esrc,
                                                   int* __restrict__ deg,
                                                   int n_edges) {
  int i = blockIdx.x * blockDim.x + threadIdx.x;
  const int stride = gridDim.x * blockDim.x;
  for (; i < n_edges; i += stride) atomicAdd(&deg[esrc[i]], 1);
}

__global__ __launch_bounds__(SCAN_B) void scan_reduce(const int* __restrict__ deg,
                                                      int* __restrict__ bsum,
                                                      int n) {
  __shared__ int s[SCAN_B];
  const int i = blockIdx.x * SCAN_B + threadIdx.x;
  s[threadIdx.x] = (i < n) ? deg[i] : 0;
  __syncthreads();
  for (int off = SCAN_B / 2; off > 0; off >>= 1) {
    if (threadIdx.x < off) s[threadIdx.x] += s[threadIdx.x + off];
    __syncthreads();
  }
  if (threadIdx.x == 0) bsum[blockIdx.x] = s[0];
}

// Single block: exclusive-scan bsum[0..nb) in place (nb <= 256), write total.
__global__ __launch_bounds__(256) void scan_bsum(int* __restrict__ bsum, int nb,
                                                 int* __restrict__ totalp) {
  __shared__ int s[256];
  const int t = threadIdx.x;
  const int v = (t < nb) ? bsum[t] : 0;
  s[t] = v;
  __syncthreads();
  for (int off = 1; off < 256; off <<= 1) {
    const int tv = (t >= off) ? s[t - off] : 0;
    __syncthreads();
    s[t] += tv;
    __syncthreads();
  }
  if (t < nb) bsum[t] = s[t] - v;  // exclusive
  if (t == 255) *totalp = s[255];
}

__global__ __launch_bounds__(SCAN_B) void scan_final(
    const int* __restrict__ deg, const int* __restrict__ bsum,
    const int* __restrict__ totalp, int* __restrict__ off,
    int* __restrict__ cursor, int n) {
  __shared__ int s[SCAN_B];
  const int t = threadIdx.x;
  const int i = blockIdx.x * SCAN_B + t;
  const int v = (i < n) ? deg[i] : 0;
  s[t] = v;
  __syncthreads();
  for (int o = 1; o < SCAN_B; o <<= 1) {
    const int tv = (t >= o) ? s[t - o] : 0;
    __syncthreads();
    s[t] += tv;
    __syncthreads();
  }
  const int excl = s[t] - v + bsum[blockIdx.x];
  if (i < n) {
    off[i] = excl;
    cursor[i] = excl;
  }
  if (blockIdx.x == 0 && t == 0) off[n] = *totalp;
}

// ---------------------------------------------------------------------------
// Fill: batched phases to keep 8 atomic round-trips in flight per thread.
// ---------------------------------------------------------------------------
__global__ __launch_bounds__(256) void fill_kernel(
    const int* __restrict__ esrc, const int* __restrict__ edst,
    const float* __restrict__ ew, int* __restrict__ cursor,
    int2* __restrict__ sedge, int n_edges) {
  const int chunk = blockIdx.x * 2048;
  int s[8];
  int2 pk[8];
  bool valid[8];
#pragma unroll
  for (int k = 0; k < 8; ++k) {
    const int e = chunk + k * 256 + threadIdx.x;
    valid[k] = e < n_edges;
    const int ee = valid[k] ? e : 0;
    s[k] = esrc[ee];
    pk[k].x = edst[ee];
    pk[k].y = __float_as_int(ew[ee]);
  }
  int pos[8];
#pragma unroll
  for (int k = 0; k < 8; ++k) {
    if (valid[k]) pos[k] = atomicAdd(&cursor[s[k]], 1);
  }
#pragma unroll
  for (int k = 0; k < 8; ++k) {
    if (valid[k]) sedge[pos[k]] = pk[k];
  }
}

// ---------------------------------------------------------------------------
// Gather: one wave per node. acc = sum_e w_e * X0[dst_e]; out = relu(acc + b).
// X0 rows are bf16 (256B/row, one coalesced uint per lane). 4 rows in flight.
// ---------------------------------------------------------------------------
__global__ __launch_bounds__(256) void gather_kernel(
    const int* __restrict__ off, const int2* __restrict__ sedge,
    const unsigned short* __restrict__ x0h, const float* __restrict__ b,
    float* __restrict__ out, int n_nodes) {
  const int wave = blockIdx.x * (blockDim.x >> 6) + (threadIdx.x >> 6);
  const int lane = threadIdx.x & 63;
  if (wave >= n_nodes) return;
  const int beg = off[wave];
  const int end = off[wave + 1];
  const unsigned* __restrict__ x0u = (const unsigned*)x0h;

  float2 a0 = {0.f, 0.f}, a1 = {0.f, 0.f};
  float2 a2 = {0.f, 0.f}, a3 = {0.f, 0.f};
  int e = beg;
  for (; e + 3 < end; e += 4) {
    const int2 e0 = sedge[e];
    const int2 e1 = sedge[e + 1];
    const int2 e2 = sedge[e + 2];
    const int2 e3 = sedge[e + 3];
    const unsigned u0 = x0u[(size_t)e0.x * 64 + lane];
    const unsigned u1 = x0u[(size_t)e1.x * 64 + lane];
    const unsigned u2 = x0u[(size_t)e2.x * 64 + lane];
    const unsigned u3 = x0u[(size_t)e3.x * 64 + lane];
    const float w0 = __int_as_float(e0.y);
    const float w1 = __int_as_float(e1.y);
    const float w2 = __int_as_float(e2.y);
    const float w3 = __int_as_float(e3.y);
    a0.x += __uint_as_float(u0 << 16) * w0;
    a0.y += __uint_as_float(u0 & 0xFFFF0000u) * w0;
    a1.x += __uint_as_float(u1 << 16) * w1;
    a1.y += __uint_as_float(u1 & 0xFFFF0000u) * w1;
    a2.x += __uint_as_float(u2 << 16) * w2;
    a2.y += __uint_as_float(u2 & 0xFFFF0000u) * w2;
    a3.x += __uint_as_float(u3 << 16) * w3;
    a3.y += __uint_as_float(u3 & 0xFFFF0000u) * w3;
  }
  for (; e < end; ++e) {
    const int2 e0 = sedge[e];
    const unsigned u0 = x0u[(size_t)e0.x * 64 + lane];
    const float w0 = __int_as_float(e0.y);
    a0.x += __uint_as_float(u0 << 16) * w0;
    a0.y += __uint_as_float(u0 & 0xFFFF0000u) * w0;
  }
  const float2 bb = ((const float2*)b)[lane];
  float2 r;
  r.x = fmaxf(a0.x + a1.x + a2.x + a3.x + bb.x, 0.f);
  r.y = fmaxf(a0.y + a1.y + a2.y + a3.y + bb.y, 0.f);
  ((float2*)out)[(size_t)wave * 64 + lane] = r;
}

// ---------------------------------------------------------------------------
// Fallback path (if ws too small for CSR): atomic scatter + epilogue.
// ---------------------------------------------------------------------------
__global__ __launch_bounds__(256) void scatter_kernel(
    const int* __restrict__ esrc, const int* __restrict__ edst,
    const float* __restrict__ ew, const unsigned short* __restrict__ x0h,
    float* __restrict__ acc, int n_edges) {
  const int lane = threadIdx.x & 63;
  const int waveId = blockIdx.x * (blockDim.x >> 6) + (threadIdx.x >> 6);
  const int nWaves = gridDim.x * (blockDim.x >> 6);
  const unsigned* __restrict__ x0u = (const unsigned*)x0h;
  for (int e = waveId; e < n_edges; e += nWaves) {
    const int s = esrc[e];
    const int d = edst[e];
    const float wt = ew[e];
    const unsigned u = x0u[(size_t)d * 64 + lane];
    float* p = acc + (size_t)s * H + lane * 2;
    atomicAdd(p, __uint_as_float(u << 16) * wt);
    atomicAdd(p + 1, __uint_as_float(u & 0xFFFF0000u) * wt);
  }
}

__global__ __launch_bounds__(256) void epilogue_kernel(
    float* __restrict__ out, const float* __restrict__ b, int n4) {
  const int i = blockIdx.x * blockDim.x + threadIdx.x;
  if (i >= n4) return;
  float4* o4 = (float4*)out;
  const float4* b4 = (const float4*)b;
  float4 v = o4[i];
  const float4 bb = b4[i & 31];
  v.x = fmaxf(v.x + bb.x, 0.f);
  v.y = fmaxf(v.y + bb.y, 0.f);
  v.z = fmaxf(v.z + bb.z, 0.f);
  v.w = fmaxf(v.w + bb.w, 0.f);
  o4[i] = v;
}

extern "C" void kernel_launch(void* const* d_in, const int* in_sizes, int n_in,
                              void* d_out, int out_size, void* d_ws, size_t ws_size,
                              hipStream_t stream) {
  const float* notes = (const float*)d_in[0];
  const float* w     = (const float*)d_in[1];
  const float* b     = (const float*)d_in[2];
  const int*   esrc  = (const int*)d_in[3];
  const int*   edst  = (const int*)d_in[4];
  const float* ew    = (const float*)d_in[5];
  const int*   gptr  = (const int*)d_in[6];

  const int n_nodes = in_sizes[0] / H;
  const int n_edges = in_sizes[3];
  float* out = (float*)d_out;

  // Workspace carve-up (256B-aligned regions).
  char* ws = (char*)d_ws;
  size_t p = 0;
  auto alloc = [&](size_t bytes) -> char* {
    char* cur = ws + p;
    p = (p + bytes + 255) & ~(size_t)255;
    return cur;
  };
  unsigned short* x0h = (unsigned short*)alloc((size_t)n_nodes * H * 2);
  int*  deg    = (int*)alloc((size_t)n_nodes * sizeof(int));
  int*  off    = (int*)alloc(((size_t)n_nodes + 1) * sizeof(int));
  int*  cur    = (int*)alloc((size_t)n_nodes * sizeof(int));
  int*  bsum   = (int*)alloc(256 * sizeof(int));
  int*  totalp = (int*)alloc(sizeof(int));
  int2* sedge  = (int2*)alloc((size_t)n_edges * sizeof(int2));
  const int nb = (n_nodes + SCAN_B - 1) / SCAN_B;
  const bool csr_ok = (p <= ws_size) && (nb <= 256);

  // GEMM (also writes concat tail rows fp32; x0 stored bf16).
  gemm_kernel<<<(n_nodes + 63) / 64, 256, 0, stream>>>(notes, w, gptr, x0h, out,
                                                       n_nodes);

  if (csr_ok) {
    hipMemsetAsync(deg, 0, (size_t)n_nodes * sizeof(int), stream);
    hist_kernel<<<2048, 256, 0, stream>>>(esrc, deg, n_edges);
    scan_reduce<<<nb, SCAN_B, 0, stream>>>(deg, bsum, n_nodes);
    scan_bsum<<<1, 256, 0, stream>>>(bsum, nb, totalp);
    scan_final<<<nb, SCAN_B, 0, stream>>>(deg, bsum, totalp, off, cur, n_nodes);
    fill_kernel<<<(n_edges + 2047) / 2048, 256, 0, stream>>>(esrc, edst, ew,
                                                             cur, sedge,
                                                             n_edges);
    gather_kernel<<<(n_nodes + 3) / 4, 256, 0, stream>>>(off, sedge, x0h, b,
                                                         out, n_nodes);
  } else {
    hipMemsetAsync(d_out, 0, (size_t)n_nodes * H * sizeof(float), stream);
    scatter_kernel<<<2048, 256, 0, stream>>>(esrc, edst, ew, x0h, out, n_edges);
    const int n4 = n_nodes * H / 4;
    epilogue_kernel<<<(n4 + 255) / 256, 256, 0, stream>>>(out, b, n4);
  }
}